// Round 16
// baseline (120.558 us; speedup 1.0000x reference)
//
#include <hip/hip_runtime.h>
#include <hip/hip_bf16.h>

#define S_LEN 2048
#define EMB 1024
#define NH 16
#define HD 64
// M = B*S = 4096 rows

typedef __attribute__((ext_vector_type(8))) __bf16 bf16x8;
typedef __attribute__((ext_vector_type(4))) float f32x4;
typedef __attribute__((ext_vector_type(16))) float f32x16;
typedef __attribute__((ext_vector_type(4))) unsigned int u32x4;

__device__ inline void gload_lds16(const void* g, void* l) {
    __builtin_amdgcn_global_load_lds(
        (const __attribute__((address_space(1))) unsigned int*)g,
        (__attribute__((address_space(3))) unsigned int*)l, 16, 0, 0);
}

// ---------------------------------------------------------------------------
// Kernel 0: fp32 -> bf16 conversion of x, qkv_w, out_w in ONE launch.
// ---------------------------------------------------------------------------
__global__ __launch_bounds__(256) void cvt_all(
    const float* __restrict__ x, const float* __restrict__ wq,
    const float* __restrict__ wo,
    __hip_bfloat16* __restrict__ xb, __hip_bfloat16* __restrict__ wqb,
    __hip_bfloat16* __restrict__ wob)
{
    const long C_X = (long)4096 * 1024 / 4;       // 1,048,576
    const long C_WQ = (long)3072 * 1024 / 4;      // 786,432
    long c = (long)blockIdx.x * 256 + threadIdx.x;
    const float* in;
    __hip_bfloat16* out;
    if (c < C_X) { in = x; out = xb; }
    else if (c < C_X + C_WQ) { in = wq; out = wqb; c -= C_X; }
    else { in = wo; out = wob; c -= C_X + C_WQ; }
    long i = c * 4;
    float4 v = *(const float4*)(in + i);
    __hip_bfloat16 b0 = __float2bfloat16(v.x);
    __hip_bfloat16 b1 = __float2bfloat16(v.y);
    __hip_bfloat16 b2 = __float2bfloat16(v.z);
    __hip_bfloat16 b3 = __float2bfloat16(v.w);
    ushort4 o = {*(unsigned short*)&b0, *(unsigned short*)&b1,
                 *(unsigned short*)&b2, *(unsigned short*)&b3};
    *(ushort4*)(out + i) = o;
}

// ---------------------------------------------------------------------------
// MFMA GEMM core (m97 structure): C = A @ B^T, BM=128, BN templated, BK=64,
// 4 waves (2x2; wave covers 64 rows x BN/2 cols). 1-D grid with bijective
// XCD swizzle (T1): sw = (bid&7)*CH + bid>>3; x = sw%NX, y = sw/NX.
// EPI=0 (BN=128): quantum epilogue (cos*cos, scatter Q/K/Vt; V via per-wave
// LDS transpose).  EPI=1 (BN=64): fp32 C store, 512 blocks -> 2/CU.
// Q is pre-scaled by 0.125*log2(e) so attention can use exp2 directly.
// ---------------------------------------------------------------------------
template <int EPI, int BN, int NX, int CH>
__global__ __launch_bounds__(256) void gemm_mfma(
    const __hip_bfloat16* __restrict__ A,   // [M][1024]
    const __hip_bfloat16* __restrict__ B,   // [N][1024]
    const float* __restrict__ qp,           // [64] (EPI=0)
    __hip_bfloat16* __restrict__ Q,         // EPI=0 outputs
    __hip_bfloat16* __restrict__ Kp,
    __hip_bfloat16* __restrict__ Vt,
    float* __restrict__ C)                  // EPI=1 output
{
    const int Kd = 1024;
    const int NI = BN / 32;                 // 16-col frags per wave
    __shared__ __align__(16) char Ash[128 * 128];
    __shared__ __align__(16) char Bsh[BN * 128];

    const int bid = blockIdx.x;
    const int sw_ = (bid & 7) * CH + (bid >> 3);
    const int m0 = (sw_ / NX) * 128;
    const int n0 = (sw_ % NX) * BN;

    const int t  = threadIdx.x;
    const int w  = t >> 6;
    const int l  = t & 63;
    const int lg = l >> 4, lm = l & 15;
    const int wr = w >> 1, wc = w & 1;

    const int r8 = l >> 3;
    const int sb = ((l & 7) * 16) ^ (r8 << 4);
    const char* srcA = (const char*)A + ((long)(m0 + w * 32 + r8) * Kd) * 2 + sb;
    const char* srcB = (const char*)B + ((long)(n0 + w * (BN / 4) + r8) * Kd) * 2 + sb;

    f32x4 acc[4][NI];
#pragma unroll
    for (int i = 0; i < 4; i++)
#pragma unroll
        for (int j = 0; j < NI; j++) acc[i][j] = (f32x4){0.f, 0.f, 0.f, 0.f};

    for (int kt = 0; kt < Kd * 2; kt += 128) {
#pragma unroll
        for (int j = 0; j < 4; j++)
            gload_lds16(srcA + (long)j * 8 * Kd * 2 + kt, Ash + (w * 32 + j * 8) * 128);
#pragma unroll
        for (int j = 0; j < NI; j++)
            gload_lds16(srcB + (long)j * 8 * Kd * 2 + kt,
                        Bsh + (w * (BN / 4) + j * 8) * 128);
        __syncthreads();
#pragma unroll
        for (int kk = 0; kk < 2; kk++) {
            bf16x8 af[4], bfr[NI];
            const int sw = (lm & 7) << 4;
            const int co = (kk * 64 + lg * 16);
#pragma unroll
            for (int mi = 0; mi < 4; mi++)
                af[mi] = *(const bf16x8*)(Ash + (wr * 64 + mi * 16 + lm) * 128 + (co ^ sw));
#pragma unroll
            for (int ni = 0; ni < NI; ni++)
                bfr[ni] = *(const bf16x8*)(Bsh + (wc * (BN / 2) + ni * 16 + lm) * 128 + (co ^ sw));
#pragma unroll
            for (int mi = 0; mi < 4; mi++)
#pragma unroll
                for (int ni = 0; ni < NI; ni++)
                    acc[mi][ni] = __builtin_amdgcn_mfma_f32_16x16x32_bf16(
                        af[mi], bfr[ni], acc[mi][ni], 0, 0, 0);
        }
        __syncthreads();
    }

    if constexpr (EPI == 0) {
        const int which = n0 >> 10;
        float cqp[NI];
#pragma unroll
        for (int ni = 0; ni < NI; ni++)
            cqp[ni] = __cosf(qp[(wc * (BN / 2) + ni * 16 + lm) & 63]);

        if (which == 2) {
            // ---- V: per-wave LDS transpose -> coalesced Vt[d][s] stores ----
            char* T = (w < 2 ? Ash : Bsh) + (w & 1) * 8192;
#pragma unroll
            for (int mi = 0; mi < 4; mi++)
#pragma unroll
                for (int r = 0; r < 4; r++)
#pragma unroll
                    for (int ni = 0; ni < NI; ni++) {
                        int row = ni * 16 + lm;            // d (0..63)
                        int col = mi * 16 + lg * 4 + r;    // s-local (0..63)
                        float val = __cosf(acc[mi][ni][r]) * cqp[ni];
                        *(__hip_bfloat16*)(T + row * 128 +
                                           ((col * 2) ^ ((row & 7) << 4))) =
                            __float2bfloat16(val);
                    }
            const int h  = ((n0 & 1023) >> 6) + wc;
            const int bh = (m0 >> 11) * NH + h;
            const int sbase = (m0 & 2047) + wr * 64;
#pragma unroll
            for (int j = 0; j < 8; j++) {
                int c = j * 64 + l;
                int d = c >> 3;
                int sc = (c & 7) * 16;
                uint4 v = *(const uint4*)(T + d * 128 + (sc ^ ((d & 7) << 4)));
                *(uint4*)((char*)(Vt + ((long)bh * HD + d) * S_LEN + sbase) + sc) = v;
            }
        } else {
#pragma unroll
            for (int mi = 0; mi < 4; mi++) {
#pragma unroll
                for (int r = 0; r < 4; r++) {
                    int m = m0 + wr * 64 + mi * 16 + lg * 4 + r;
                    int b = m >> 11, s = m & 2047;
#pragma unroll
                    for (int ni = 0; ni < NI; ni++) {
                        int n = n0 + wc * (BN / 2) + ni * 16 + lm;
                        int d = n & 63;
                        int h = (n & 1023) >> 6;
                        int bh = b * NH + h;
                        float val = __cosf(acc[mi][ni][r]) * cqp[ni];
                        if (which == 0)  // 0.125*log2(e) folded for exp2 softmax
                            Q[((long)bh * S_LEN + s) * HD + d] =
                                __float2bfloat16(val * 0.180336880f);
                        else
                            Kp[((long)bh * S_LEN + s) * HD + d] = __float2bfloat16(val);
                    }
                }
            }
        }
    } else {
#pragma unroll
        for (int mi = 0; mi < 4; mi++)
#pragma unroll
            for (int r = 0; r < 4; r++) {
                int m = m0 + wr * 64 + mi * 16 + lg * 4 + r;
#pragma unroll
                for (int ni = 0; ni < NI; ni++) {
                    int n = n0 + wc * (BN / 2) + ni * 16 + lm;
                    C[(long)m * 1024 + n] = acc[mi][ni][r];
                }
            }
    }
}

// ---------------------------------------------------------------------------
// Kernel 2: MFMA flash attention. r13 core (2x2 wave split, 32x32x16,
// in-register P via cvt_pk + permlane32_swap) + T15 QK-AHEAD PIPELINE:
// 3 LDS buffers staged 2 tiles ahead; per tile the order is
//   STAGE(t+2) -> QK(t+1) [MFMA, independent] -> SM(t) [VALU, hides under
//   QK's in-flight MFMAs] -> PV(t) -> one barrier.
// Buffer roles (K-read t+1, V-read t, write t+2) are distinct mod 3 ->
// race-free with one barrier/tile. 48KB LDS -> 3 blocks/CU.
// ---------------------------------------------------------------------------
__global__ __launch_bounds__(256, 3) void attn_mfma(
    const __hip_bfloat16* __restrict__ Q,
    const __hip_bfloat16* __restrict__ K,
    const __hip_bfloat16* __restrict__ Vt,  // [B,H,D,S]
    __hip_bfloat16* __restrict__ O)
{
    __shared__ __align__(16) char smem[3 * 16384];
    // buffer i: K tile at smem+i*16384 (64 keys x 128B, swz), V at +8192

    const int L  = blockIdx.x;               // 0..1023
    const int bh = (L & 7) + (L >> 8) * 8;   // XCD swizzle (r12-proven)
    const int q0 = ((L >> 3) & 31) * 64;
    const int b  = bh >> 4, h = bh & 15;
    const int t  = threadIdx.x;
    const int w  = t >> 6;                   // wave 0..3
    const int qi = w & 1;                    // q-half (32 rows)
    const int ki = w >> 1;                   // key-half (32 keys)
    const int l  = t & 63;
    const int lo5 = l & 31;
    const int hi  = l >> 5;

    // Q fragments (pre-scaled by 0.125*log2e): q = q0 + qi*32 + lo5
    const char* Qr =
        (const char*)(Q + ((long)bh * S_LEN + q0 + qi * 32 + lo5) * HD);
    bf16x8 qf[4];
#pragma unroll
    for (int ks = 0; ks < 4; ks++)
        qf[ks] = *(const bf16x8*)(Qr + ks * 32 + hi * 16);

    f32x16 oacc[2] = {};
    float lsum = 0.f;
    const float EXPB = 11.54156033f;  // 8 * log2(e)

    const char* Kgb = (const char*)(K + (long)bh * S_LEN * HD);
    const char* Vgb = (const char*)(Vt + (long)bh * HD * S_LEN);

    // DMA staging (r13-proven): lane l covers LDS row w*8+(l>>3) (+32 chunk2),
    // 16B col (l&7). Linear LDS dest; source byte pre-swizzled by ((row&7)<<4).
    const int swb = ((l & 7) * 16) ^ (((l >> 3) & 7) << 4);
    const int row0 = w * 8 + (l >> 3);
    const char* Ksrc  = Kgb + (long)row0 * 128 + swb;                  // +kt*128
    const char* Vsrc0 = Vgb + (long)row0 * (S_LEN * 2) + swb;          // +kt*2
    const char* Vsrc1 = Vgb + (long)(row0 + 32) * (S_LEN * 2) + swb;   // +kt*2

#define STAGE(buf, nk)                                                         \
    do {                                                                       \
        char* base_ = smem + (buf) * 16384;                                    \
        gload_lds16(Ksrc + (long)(nk) * 128, base_ + w * 1024);                \
        gload_lds16(Ksrc + (long)((nk) + 32) * 128, base_ + w * 1024 + 4096);  \
        gload_lds16(Vsrc0 + (long)(nk) * 2, base_ + 8192 + w * 1024);          \
        gload_lds16(Vsrc1 + (long)(nk) * 2, base_ + 8192 + w * 1024 + 4096);   \
    } while (0)

    const int swr = (lo5 & 7) << 4;  // read swizzle (row&7 == lo5&7 here)

    // QK^T on one staged K tile: S^T - EXPB (bias folded into acc init)
    auto QK = [&](const char* Kc) {
        f32x16 s;
#pragma unroll
        for (int r = 0; r < 16; r++) s[r] = -EXPB;
        const char* Krow = Kc + (ki * 32 + lo5) * 128;
        __builtin_amdgcn_s_setprio(1);
#pragma unroll
        for (int ks = 0; ks < 4; ks++) {
            bf16x8 kf = *(const bf16x8*)(Krow + ((ks * 32 + hi * 16) ^ swr));
            s = __builtin_amdgcn_mfma_f32_32x32x16_bf16(kf, qf[ks], s, 0, 0, 0);
        }
        __builtin_amdgcn_s_setprio(0);
        return s;  // s[r] = S[key=ki*32+(r&3)+8*(r>>2)+4*hi][q=lo5] - EXPB
    };

    // prologue: stage tiles 0,1; drain; compute QK(0)
    STAGE(0, 0);
    STAGE(1, 64);
    __syncthreads();
    f32x16 sp = QK(smem);

    int cur = 0, nxt = 1, stg = 2;
    for (int kt = 0; kt < S_LEN; kt += 64) {
        const bool more = (kt + 64 < S_LEN);
        if (kt + 128 < S_LEN) STAGE(stg, kt + 128);

        // ---- QK(t+1): independent MFMA, issued before SM so softmax VALU
        //      runs while these MFMAs are in flight ----
        f32x16 sn;
        if (more) sn = QK(smem + nxt * 16384);

        // ---- SM(t): softmax + in-register P (cvt_pk + permlane) ----
        float p[16];
#pragma unroll
        for (int r = 0; r < 16; r++) p[r] = __builtin_amdgcn_exp2f(sp[r]);
#pragma unroll
        for (int r = 0; r < 16; r += 4)
            lsum += (p[r] + p[r + 1]) + (p[r + 2] + p[r + 3]);
        unsigned c0, c1, c2, c3, c4, c5, c6, c7;
        asm("v_cvt_pk_bf16_f32 %0, %1, %2" : "=v"(c0) : "v"(p[0]),  "v"(p[1]));
        asm("v_cvt_pk_bf16_f32 %0, %1, %2" : "=v"(c1) : "v"(p[2]),  "v"(p[3]));
        asm("v_cvt_pk_bf16_f32 %0, %1, %2" : "=v"(c2) : "v"(p[4]),  "v"(p[5]));
        asm("v_cvt_pk_bf16_f32 %0, %1, %2" : "=v"(c3) : "v"(p[6]),  "v"(p[7]));
        asm("v_cvt_pk_bf16_f32 %0, %1, %2" : "=v"(c4) : "v"(p[8]),  "v"(p[9]));
        asm("v_cvt_pk_bf16_f32 %0, %1, %2" : "=v"(c5) : "v"(p[10]), "v"(p[11]));
        asm("v_cvt_pk_bf16_f32 %0, %1, %2" : "=v"(c6) : "v"(p[12]), "v"(p[13]));
        asm("v_cvt_pk_bf16_f32 %0, %1, %2" : "=v"(c7) : "v"(p[14]), "v"(p[15]));
        asm("v_permlane32_swap_b32 %0, %1" : "+v"(c0), "+v"(c2));
        asm("v_permlane32_swap_b32 %0, %1" : "+v"(c1), "+v"(c3));
        asm("v_permlane32_swap_b32 %0, %1" : "+v"(c4), "+v"(c6));
        asm("v_permlane32_swap_b32 %0, %1" : "+v"(c5), "+v"(c7));
        u32x4 w0 = {c0, c1, c2, c3};
        u32x4 w1 = {c4, c5, c6, c7};
        bf16x8 pa0 = __builtin_bit_cast(bf16x8, w0);  // keys ki*32 + 0..15
        bf16x8 pa1 = __builtin_bit_cast(bf16x8, w1);  // keys ki*32 + 16..31

        // ---- PV(t) over this wave's 32 keys (V from buf cur) ----
        const char* Vc = smem + cur * 16384 + 8192;
        __builtin_amdgcn_s_setprio(1);
#pragma unroll
        for (int db = 0; db < 2; db++) {
            const char* Vrow = Vc + (db * 32 + lo5) * 128;
            bf16x8 vf0 = *(const bf16x8*)(Vrow + ((ki * 64 + hi * 16) ^ swr));
            bf16x8 vf1 = *(const bf16x8*)(Vrow + ((ki * 64 + 32 + hi * 16) ^ swr));
            oacc[db] = __builtin_amdgcn_mfma_f32_32x32x16_bf16(pa0, vf0, oacc[db], 0, 0, 0);
            oacc[db] = __builtin_amdgcn_mfma_f32_32x32x16_bf16(pa1, vf1, oacc[db], 0, 0, 0);
        }
        __builtin_amdgcn_s_setprio(0);

        __syncthreads();  // drains STAGE(t+2) (had SM+QK+PV to land);
                          // publishes buf stg; protects cur until next write
        int tmp = cur; cur = nxt; nxt = stg; stg = tmp;
        if (more) sp = sn;
    }
#undef STAGE

    // ---- combine key-halves: lane lo5 holds q=lo5 after hi-reduce ----
    lsum += __shfl_xor(lsum, 32, 64);
    __syncthreads();  // main-loop LDS reads done; reuse smem
    float* Osh = (float*)smem;               // 2 qi regions x 32x64 f32 = 16KB
    float* Lsh = (float*)(smem + 16384);     // 2 qi regions x 64 f32
    if (ki == 1) {
        float* dst = Osh + qi * 2048;
#pragma unroll
        for (int db = 0; db < 2; db++)
#pragma unroll
            for (int r = 0; r < 16; r++)
                dst[(db * 16 + r) * 64 + l] = oacc[db][r];  // lane-major: no conflicts
        Lsh[qi * 64 + l] = lsum;
    }
    __syncthreads();
    if (ki == 0) {
        const float* src = Osh + qi * 2048;
#pragma unroll
        for (int db = 0; db < 2; db++)
#pragma unroll
            for (int r = 0; r < 16; r++)
                oacc[db][r] += src[(db * 16 + r) * 64 + l];
        lsum += Lsh[qi * 64 + l];
        float inv = 1.f / lsum;  // valid for q = lo5
#pragma unroll
        for (int r = 0; r < 16; r++) {
            int qr = (r & 3) + 8 * (r >> 2) + 4 * hi;
            float invr = __shfl(inv, qr, 32);
            int qrow = q0 + qi * 32 + qr;
            long base = ((long)b * S_LEN + qrow) * EMB + h * HD;
            O[base + lo5]      = __float2bfloat16(oacc[0][r] * invr);
            O[base + 32 + lo5] = __float2bfloat16(oacc[1][r] * invr);
        }
    }
}

extern "C" void kernel_launch(void* const* d_in, const int* in_sizes, int n_in,
                              void* d_out, int out_size, void* d_ws, size_t ws_size,
                              hipStream_t stream) {
    const float* x     = (const float*)d_in[0];   // [2,2048,1024]
    const float* qkv_w = (const float*)d_in[1];   // [3072,1024]
    const float* out_w = (const float*)d_in[2];   // [1024,1024]
    const float* qp    = (const float*)d_in[3];   // [64]
    float* out = (float*)d_out;                   // [2,2048,1024] fp32

    const long NELEM = (long)2 * S_LEN * EMB;     // 4,194,304
    __hip_bfloat16* Q   = (__hip_bfloat16*)d_ws;  // [B,H,S,D] (x 0.125*log2e)
    __hip_bfloat16* K   = Q + NELEM;              // [B,H,S,D]
    __hip_bfloat16* Vt  = K + NELEM;              // [B,H,D,S]
    __hip_bfloat16* O   = Vt + NELEM;             // [B,S,E]
    __hip_bfloat16* xb  = O + NELEM;              // [4096][1024]
    __hip_bfloat16* wqb = xb + NELEM;             // [3072][1024]
    __hip_bfloat16* wob = wqb + (long)3072 * 1024;// [1024][1024]

    dim3 blk(256);
    cvt_all<<<dim3(8192), blk, 0, stream>>>(x, qkv_w, out_w, xb, wqb, wob);
    // EPI=0: BN=128, grid 24x32=768 (1-D, XCD-swizzled: CH=96)
    gemm_mfma<0, 128, 24, 96><<<dim3(768), blk, 0, stream>>>(
        xb, wqb, qp, Q, K, Vt, nullptr);
    attn_mfma<<<dim3(1024), blk, 0, stream>>>(Q, K, Vt, O);
    // EPI=1: BN=64, grid 16x32=512 (2 blocks/CU; CH=64)
    gemm_mfma<1, 64, 16, 64><<<dim3(512), blk, 0, stream>>>(
        O, wob, nullptr, nullptr, nullptr, nullptr, out);
}

// Round 17
// 115.698 us; speedup vs baseline: 1.0420x; 1.0420x over previous
//
#include <hip/hip_runtime.h>
#include <hip/hip_bf16.h>

#define S_LEN 2048
#define EMB 1024
#define NH 16
#define HD 64
// M = B*S = 4096 rows

typedef __attribute__((ext_vector_type(8))) __bf16 bf16x8;
typedef __attribute__((ext_vector_type(4))) float f32x4;
typedef __attribute__((ext_vector_type(16))) float f32x16;
typedef __attribute__((ext_vector_type(4))) unsigned int u32x4;

__device__ inline void gload_lds16(const void* g, void* l) {
    __builtin_amdgcn_global_load_lds(
        (const __attribute__((address_space(1))) unsigned int*)g,
        (__attribute__((address_space(3))) unsigned int*)l, 16, 0, 0);
}

// ---------------------------------------------------------------------------
// Kernel 0: fp32 -> bf16 conversion of x, qkv_w, out_w in ONE launch.
// ---------------------------------------------------------------------------
__global__ __launch_bounds__(256) void cvt_all(
    const float* __restrict__ x, const float* __restrict__ wq,
    const float* __restrict__ wo,
    __hip_bfloat16* __restrict__ xb, __hip_bfloat16* __restrict__ wqb,
    __hip_bfloat16* __restrict__ wob)
{
    const long C_X = (long)4096 * 1024 / 4;       // 1,048,576
    const long C_WQ = (long)3072 * 1024 / 4;      // 786,432
    long c = (long)blockIdx.x * 256 + threadIdx.x;
    const float* in;
    __hip_bfloat16* out;
    if (c < C_X) { in = x; out = xb; }
    else if (c < C_X + C_WQ) { in = wq; out = wqb; c -= C_X; }
    else { in = wo; out = wob; c -= C_X + C_WQ; }
    long i = c * 4;
    float4 v = *(const float4*)(in + i);
    __hip_bfloat16 b0 = __float2bfloat16(v.x);
    __hip_bfloat16 b1 = __float2bfloat16(v.y);
    __hip_bfloat16 b2 = __float2bfloat16(v.z);
    __hip_bfloat16 b3 = __float2bfloat16(v.w);
    ushort4 o = {*(unsigned short*)&b0, *(unsigned short*)&b1,
                 *(unsigned short*)&b2, *(unsigned short*)&b3};
    *(ushort4*)(out + i) = o;
}

// ---------------------------------------------------------------------------
// MFMA GEMM core (m97 structure): C = A @ B^T, BM=128, BN templated, BK=64,
// 4 waves (2x2; wave covers 64 rows x BN/2 cols). 1-D grid with bijective
// XCD swizzle (T1): sw = (bid&7)*CH + bid>>3; x = sw%NX, y = sw/NX.
// EPI=0 (BN=128): quantum epilogue (cos*cos, scatter Q/K/Vt; V via per-wave
// LDS transpose).  EPI=1 (BN=64): fp32 C store, 512 blocks -> 2/CU.
// Q is pre-scaled by 0.125*log2(e) so attention can use exp2 directly.
// ---------------------------------------------------------------------------
template <int EPI, int BN, int NX, int CH>
__global__ __launch_bounds__(256) void gemm_mfma(
    const __hip_bfloat16* __restrict__ A,   // [M][1024]
    const __hip_bfloat16* __restrict__ B,   // [N][1024]
    const float* __restrict__ qp,           // [64] (EPI=0)
    __hip_bfloat16* __restrict__ Q,         // EPI=0 outputs
    __hip_bfloat16* __restrict__ Kp,
    __hip_bfloat16* __restrict__ Vt,
    float* __restrict__ C)                  // EPI=1 output
{
    const int Kd = 1024;
    const int NI = BN / 32;                 // 16-col frags per wave
    __shared__ __align__(16) char Ash[128 * 128];
    __shared__ __align__(16) char Bsh[BN * 128];

    const int bid = blockIdx.x;
    const int sw_ = (bid & 7) * CH + (bid >> 3);
    const int m0 = (sw_ / NX) * 128;
    const int n0 = (sw_ % NX) * BN;

    const int t  = threadIdx.x;
    const int w  = t >> 6;
    const int l  = t & 63;
    const int lg = l >> 4, lm = l & 15;
    const int wr = w >> 1, wc = w & 1;

    const int r8 = l >> 3;
    const int sb = ((l & 7) * 16) ^ (r8 << 4);
    const char* srcA = (const char*)A + ((long)(m0 + w * 32 + r8) * Kd) * 2 + sb;
    const char* srcB = (const char*)B + ((long)(n0 + w * (BN / 4) + r8) * Kd) * 2 + sb;

    f32x4 acc[4][NI];
#pragma unroll
    for (int i = 0; i < 4; i++)
#pragma unroll
        for (int j = 0; j < NI; j++) acc[i][j] = (f32x4){0.f, 0.f, 0.f, 0.f};

    for (int kt = 0; kt < Kd * 2; kt += 128) {
#pragma unroll
        for (int j = 0; j < 4; j++)
            gload_lds16(srcA + (long)j * 8 * Kd * 2 + kt, Ash + (w * 32 + j * 8) * 128);
#pragma unroll
        for (int j = 0; j < NI; j++)
            gload_lds16(srcB + (long)j * 8 * Kd * 2 + kt,
                        Bsh + (w * (BN / 4) + j * 8) * 128);
        __syncthreads();
#pragma unroll
        for (int kk = 0; kk < 2; kk++) {
            bf16x8 af[4], bfr[NI];
            const int sw = (lm & 7) << 4;
            const int co = (kk * 64 + lg * 16);
#pragma unroll
            for (int mi = 0; mi < 4; mi++)
                af[mi] = *(const bf16x8*)(Ash + (wr * 64 + mi * 16 + lm) * 128 + (co ^ sw));
#pragma unroll
            for (int ni = 0; ni < NI; ni++)
                bfr[ni] = *(const bf16x8*)(Bsh + (wc * (BN / 2) + ni * 16 + lm) * 128 + (co ^ sw));
#pragma unroll
            for (int mi = 0; mi < 4; mi++)
#pragma unroll
                for (int ni = 0; ni < NI; ni++)
                    acc[mi][ni] = __builtin_amdgcn_mfma_f32_16x16x32_bf16(
                        af[mi], bfr[ni], acc[mi][ni], 0, 0, 0);
        }
        __syncthreads();
    }

    if constexpr (EPI == 0) {
        const int which = n0 >> 10;
        float cqp[NI];
#pragma unroll
        for (int ni = 0; ni < NI; ni++)
            cqp[ni] = __cosf(qp[(wc * (BN / 2) + ni * 16 + lm) & 63]);

        if (which == 2) {
            // ---- V: per-wave LDS transpose -> coalesced Vt[d][s] stores ----
            char* T = (w < 2 ? Ash : Bsh) + (w & 1) * 8192;
#pragma unroll
            for (int mi = 0; mi < 4; mi++)
#pragma unroll
                for (int r = 0; r < 4; r++)
#pragma unroll
                    for (int ni = 0; ni < NI; ni++) {
                        int row = ni * 16 + lm;            // d (0..63)
                        int col = mi * 16 + lg * 4 + r;    // s-local (0..63)
                        float val = __cosf(acc[mi][ni][r]) * cqp[ni];
                        *(__hip_bfloat16*)(T + row * 128 +
                                           ((col * 2) ^ ((row & 7) << 4))) =
                            __float2bfloat16(val);
                    }
            const int h  = ((n0 & 1023) >> 6) + wc;
            const int bh = (m0 >> 11) * NH + h;
            const int sbase = (m0 & 2047) + wr * 64;
#pragma unroll
            for (int j = 0; j < 8; j++) {
                int c = j * 64 + l;
                int d = c >> 3;
                int sc = (c & 7) * 16;
                uint4 v = *(const uint4*)(T + d * 128 + (sc ^ ((d & 7) << 4)));
                *(uint4*)((char*)(Vt + ((long)bh * HD + d) * S_LEN + sbase) + sc) = v;
            }
        } else {
#pragma unroll
            for (int mi = 0; mi < 4; mi++) {
#pragma unroll
                for (int r = 0; r < 4; r++) {
                    int m = m0 + wr * 64 + mi * 16 + lg * 4 + r;
                    int b = m >> 11, s = m & 2047;
#pragma unroll
                    for (int ni = 0; ni < NI; ni++) {
                        int n = n0 + wc * (BN / 2) + ni * 16 + lm;
                        int d = n & 63;
                        int h = (n & 1023) >> 6;
                        int bh = b * NH + h;
                        float val = __cosf(acc[mi][ni][r]) * cqp[ni];
                        if (which == 0)  // 0.125*log2(e) folded for exp2 softmax
                            Q[((long)bh * S_LEN + s) * HD + d] =
                                __float2bfloat16(val * 0.180336880f);
                        else
                            Kp[((long)bh * S_LEN + s) * HD + d] = __float2bfloat16(val);
                    }
                }
            }
        }
    } else {
#pragma unroll
        for (int mi = 0; mi < 4; mi++)
#pragma unroll
            for (int r = 0; r < 4; r++) {
                int m = m0 + wr * 64 + mi * 16 + lg * 4 + r;
#pragma unroll
                for (int ni = 0; ni < NI; ni++) {
                    int n = n0 + wc * (BN / 2) + ni * 16 + lm;
                    C[(long)m * 1024 + n] = acc[mi][ni][r];
                }
            }
    }
}

// ---------------------------------------------------------------------------
// Kernel 2: MFMA flash attention — r13/r15 kernel verbatim (measured 50us,
// best of the attn family; r6/r9/r10/r14/r16 structural variants all lost to
// it on occupancy). QBLK=64, grid 1024, XCD swizzle, double-buffered K/V DMA
// (one barrier/tile), 4 waves split 2x2 over (q-half, key-half), 32x32x16
// MFMA, in-register P (cvt_pk + permlane32_swap, r8-verified), -8*log2e
// folded into the QK accumulator init, 32KB LDS -> 4 blocks/CU.
// ---------------------------------------------------------------------------
__global__ __launch_bounds__(256, 4) void attn_mfma(
    const __hip_bfloat16* __restrict__ Q,
    const __hip_bfloat16* __restrict__ K,
    const __hip_bfloat16* __restrict__ Vt,  // [B,H,D,S]
    __hip_bfloat16* __restrict__ O)
{
    __shared__ __align__(16) char Ksh[2][64 * 128];  // 64 keys x 64 d (swz)
    __shared__ __align__(16) char Vsh[2][64 * 128];  // 64 d x 64 keys (swz)

    const int L  = blockIdx.x;               // 0..1023
    const int bh = (L & 7) + (L >> 8) * 8;   // XCD swizzle (r12-proven)
    const int q0 = ((L >> 3) & 31) * 64;
    const int b  = bh >> 4, h = bh & 15;
    const int t  = threadIdx.x;
    const int w  = t >> 6;                   // wave 0..3
    const int qi = w & 1;                    // q-half (32 rows)
    const int ki = w >> 1;                   // key-half (32 keys)
    const int l  = t & 63;
    const int lo5 = l & 31;
    const int hi  = l >> 5;

    // Q fragments (pre-scaled by 0.125*log2e): q = q0 + qi*32 + lo5
    const char* Qr =
        (const char*)(Q + ((long)bh * S_LEN + q0 + qi * 32 + lo5) * HD);
    bf16x8 qf[4];
#pragma unroll
    for (int ks = 0; ks < 4; ks++)
        qf[ks] = *(const bf16x8*)(Qr + ks * 32 + hi * 16);

    f32x16 oacc[2] = {};
    float lsum = 0.f;
    const float EXPB = 11.54156033f;  // 8 * log2(e)

    const char* Kgb = (const char*)(K + (long)bh * S_LEN * HD);
    const char* Vgb = (const char*)(Vt + (long)bh * HD * S_LEN);

    // DMA staging: lane l covers LDS row w*8+(l>>3) (+32 chunk2), 16B col
    // (l&7). Linear LDS dest; source byte pre-swizzled by ((row&7)<<4).
    const int swb = ((l & 7) * 16) ^ (((l >> 3) & 7) << 4);
    const int row0 = w * 8 + (l >> 3);
    const char* Ksrc  = Kgb + (long)row0 * 128 + swb;                  // +kt*128
    const char* Vsrc0 = Vgb + (long)row0 * (S_LEN * 2) + swb;          // +kt*2
    const char* Vsrc1 = Vgb + (long)(row0 + 32) * (S_LEN * 2) + swb;   // +kt*2

    // prologue: stage tile 0 into buffer 0
    gload_lds16(Ksrc, Ksh[0] + w * 1024);
    gload_lds16(Ksrc + 32 * 128, Ksh[0] + w * 1024 + 4096);
    gload_lds16(Vsrc0, Vsh[0] + w * 1024);
    gload_lds16(Vsrc1, Vsh[0] + w * 1024 + 4096);

    const int swr = (lo5 & 7) << 4;  // read swizzle (row&7 == lo5&7 here)
    int cur = 0;
    for (int kt = 0; kt < S_LEN; kt += 64) {
        __syncthreads();  // vmcnt(0) drained -> buf[cur] staged; alt reads done

        if (kt + 64 < S_LEN) {  // stage next tile into alternate buffer
            int nk = kt + 64;
            gload_lds16(Ksrc + (long)nk * 128, Ksh[cur ^ 1] + w * 1024);
            gload_lds16(Ksrc + (long)(nk + 32) * 128, Ksh[cur ^ 1] + w * 1024 + 4096);
            gload_lds16(Vsrc0 + (long)nk * 2, Vsh[cur ^ 1] + w * 1024);
            gload_lds16(Vsrc1 + (long)nk * 2, Vsh[cur ^ 1] + w * 1024 + 4096);
        }

        const char* Kc = Ksh[cur];
        const char* Vc = Vsh[cur];

        // ---- S^T - EXPB = K Q^T + (-EXPB): acc INIT carries the bias ----
        f32x16 s;
#pragma unroll
        for (int r = 0; r < 16; r++) s[r] = -EXPB;
        const char* Krow = Kc + (ki * 32 + lo5) * 128;
        __builtin_amdgcn_s_setprio(1);
#pragma unroll
        for (int ks = 0; ks < 4; ks++) {
            bf16x8 kf = *(const bf16x8*)(Krow + ((ks * 32 + hi * 16) ^ swr));
            s = __builtin_amdgcn_mfma_f32_32x32x16_bf16(kf, qf[ks], s, 0, 0, 0);
        }
        __builtin_amdgcn_s_setprio(0);
        // s[r] = S[key=ki*32+(r&3)+8*(r>>2)+4*hi][q=lo5] - EXPB

        // ---- softmax + in-register P->PA (cvt_pk + permlane, r8-verified) --
        float p[16];
#pragma unroll
        for (int r = 0; r < 16; r++) p[r] = __builtin_amdgcn_exp2f(s[r]);
#pragma unroll
        for (int r = 0; r < 16; r += 4)
            lsum += (p[r] + p[r + 1]) + (p[r + 2] + p[r + 3]);
        unsigned c0, c1, c2, c3, c4, c5, c6, c7;
        asm("v_cvt_pk_bf16_f32 %0, %1, %2" : "=v"(c0) : "v"(p[0]),  "v"(p[1]));
        asm("v_cvt_pk_bf16_f32 %0, %1, %2" : "=v"(c1) : "v"(p[2]),  "v"(p[3]));
        asm("v_cvt_pk_bf16_f32 %0, %1, %2" : "=v"(c2) : "v"(p[4]),  "v"(p[5]));
        asm("v_cvt_pk_bf16_f32 %0, %1, %2" : "=v"(c3) : "v"(p[6]),  "v"(p[7]));
        asm("v_cvt_pk_bf16_f32 %0, %1, %2" : "=v"(c4) : "v"(p[8]),  "v"(p[9]));
        asm("v_cvt_pk_bf16_f32 %0, %1, %2" : "=v"(c5) : "v"(p[10]), "v"(p[11]));
        asm("v_cvt_pk_bf16_f32 %0, %1, %2" : "=v"(c6) : "v"(p[12]), "v"(p[13]));
        asm("v_cvt_pk_bf16_f32 %0, %1, %2" : "=v"(c7) : "v"(p[14]), "v"(p[15]));
        asm("v_permlane32_swap_b32 %0, %1" : "+v"(c0), "+v"(c2));
        asm("v_permlane32_swap_b32 %0, %1" : "+v"(c1), "+v"(c3));
        asm("v_permlane32_swap_b32 %0, %1" : "+v"(c4), "+v"(c6));
        asm("v_permlane32_swap_b32 %0, %1" : "+v"(c5), "+v"(c7));
        u32x4 w0 = {c0, c1, c2, c3};
        u32x4 w1 = {c4, c5, c6, c7};
        bf16x8 pa0 = __builtin_bit_cast(bf16x8, w0);  // keys ki*32 + 0..15
        bf16x8 pa1 = __builtin_bit_cast(bf16x8, w1);  // keys ki*32 + 16..31

        // ---- O += P V over this wave's 32 keys ----
        __builtin_amdgcn_s_setprio(1);
#pragma unroll
        for (int db = 0; db < 2; db++) {
            const char* Vrow = Vc + (db * 32 + lo5) * 128;
            bf16x8 vf0 = *(const bf16x8*)(Vrow + ((ki * 64 + hi * 16) ^ swr));
            bf16x8 vf1 = *(const bf16x8*)(Vrow + ((ki * 64 + 32 + hi * 16) ^ swr));
            oacc[db] = __builtin_amdgcn_mfma_f32_32x32x16_bf16(pa0, vf0, oacc[db], 0, 0, 0);
            oacc[db] = __builtin_amdgcn_mfma_f32_32x32x16_bf16(pa1, vf1, oacc[db], 0, 0, 0);
        }
        __builtin_amdgcn_s_setprio(0);
        cur ^= 1;
    }

    // ---- combine key-halves: lane lo5 holds q=lo5 after hi-reduce ----
    lsum += __shfl_xor(lsum, 32, 64);
    __syncthreads();  // main-loop LDS reads done; reuse Ksh/Vsh
    float* Osh = (float*)Ksh;        // 2 qi regions x 32x64 floats = 16 KB
    float* Lsh = (float*)Vsh;        // 2 qi regions x 64 floats
    if (ki == 1) {
        float* dst = Osh + qi * 2048;
#pragma unroll
        for (int db = 0; db < 2; db++)
#pragma unroll
            for (int r = 0; r < 16; r++)
                dst[(db * 16 + r) * 64 + l] = oacc[db][r];  // lane-major: no conflicts
        Lsh[qi * 64 + l] = lsum;
    }
    __syncthreads();
    if (ki == 0) {
        const float* src = Osh + qi * 2048;
#pragma unroll
        for (int db = 0; db < 2; db++)
#pragma unroll
            for (int r = 0; r < 16; r++)
                oacc[db][r] += src[(db * 16 + r) * 64 + l];
        lsum += Lsh[qi * 64 + l];
        float inv = 1.f / lsum;  // valid for q = lo5
#pragma unroll
        for (int r = 0; r < 16; r++) {
            int qr = (r & 3) + 8 * (r >> 2) + 4 * hi;
            float invr = __shfl(inv, qr, 32);
            int qrow = q0 + qi * 32 + qr;
            long base = ((long)b * S_LEN + qrow) * EMB + h * HD;
            O[base + lo5]      = __float2bfloat16(oacc[0][r] * invr);
            O[base + 32 + lo5] = __float2bfloat16(oacc[1][r] * invr);
        }
    }
}

extern "C" void kernel_launch(void* const* d_in, const int* in_sizes, int n_in,
                              void* d_out, int out_size, void* d_ws, size_t ws_size,
                              hipStream_t stream) {
    const float* x     = (const float*)d_in[0];   // [2,2048,1024]
    const float* qkv_w = (const float*)d_in[1];   // [3072,1024]
    const float* out_w = (const float*)d_in[2];   // [1024,1024]
    const float* qp    = (const float*)d_in[3];   // [64]
    float* out = (float*)d_out;                   // [2,2048,1024] fp32

    const long NELEM = (long)2 * S_LEN * EMB;     // 4,194,304
    __hip_bfloat16* Q   = (__hip_bfloat16*)d_ws;  // [B,H,S,D] (x 0.125*log2e)
    __hip_bfloat16* K   = Q + NELEM;              // [B,H,S,D]
    __hip_bfloat16* Vt  = K + NELEM;              // [B,H,D,S]
    __hip_bfloat16* O   = Vt + NELEM;             // [B,S,E]
    __hip_bfloat16* xb  = O + NELEM;              // [4096][1024]
    __hip_bfloat16* wqb = xb + NELEM;             // [3072][1024]
    __hip_bfloat16* wob = wqb + (long)3072 * 1024;// [1024][1024]

    dim3 blk(256);
    cvt_all<<<dim3(8192), blk, 0, stream>>>(x, qkv_w, out_w, xb, wqb, wob);
    // EPI=0: BN=128, grid 24x32=768 (1-D, XCD-swizzled: CH=96)
    gemm_mfma<0, 128, 24, 96><<<dim3(768), blk, 0, stream>>>(
        xb, wqb, qp, Q, K, Vt, nullptr);
    attn_mfma<<<dim3(1024), blk, 0, stream>>>(Q, K, Vt, O);
    // EPI=1: BN=64, grid 16x32=512 (2 blocks/CU; CH=64)
    gemm_mfma<1, 64, 16, 64><<<dim3(512), blk, 0, stream>>>(
        O, wob, nullptr, nullptr, nullptr, nullptr, out);
}